// Round 2
// baseline (6408845.703 us; speedup 1.0000x reference)
//
#include <hip/hip_runtime.h>
#include <hip/hip_bf16.h>

#define B_ 32
#define T_ 512
#define E_ 256
#define H_ 512
#define L_ 50
#define NBLK 32          // worker blocks (all on ONE XCD)
#define NGRID 256        // launched blocks; non-winners exit
#define WFLAGS 128       // per-WAVE flags per step (32 blocks x 4 waves), 1 byte each

typedef __attribute__((ext_vector_type(8))) short short8;
typedef __attribute__((ext_vector_type(4))) float v4f;
typedef __attribute__((ext_vector_type(4))) int i4;
typedef unsigned long long u64;

__device__ __forceinline__ unsigned short f2bf(float f){
    union { float f; unsigned u; } v; v.f = f;
    unsigned u = v.u;
    u += 0x7fffu + ((u >> 16) & 1u);   // RNE
    return (unsigned short)(u >> 16);
}
// native-transcendental activations: v_exp_f32 + v_rcp_f32 paths (~1e-6 rel err,
// far below the bf16 rounding already in the h pipeline)
__device__ __forceinline__ float fastsig(float x){
    return __builtin_amdgcn_rcpf(1.0f + __expf(-x));
}
__device__ __forceinline__ float fasttanh(float x){
    return 1.0f - 2.0f * __builtin_amdgcn_rcpf(__expf(2.0f * x) + 1.0f);
}

__device__ __forceinline__ float qredmax(float v){
    v = fmaxf(v, __shfl_xor(v, 1, 64));
    v = fmaxf(v, __shfl_xor(v, 2, 64));
    v = fmaxf(v, __shfl_xor(v, 4, 64));
    v = fmaxf(v, __shfl_xor(v, 8, 64));
    return v;
}
__device__ __forceinline__ float qredsum(float v){
    v += __shfl_xor(v, 1, 64);
    v += __shfl_xor(v, 2, 64);
    v += __shfl_xor(v, 4, 64);
    v += __shfl_xor(v, 8, 64);
    return v;
}

// sc0-only memory ops: bypass L1, hit the XCD-shared L2 (intra-XCD coherent).
__device__ __forceinline__ i4 load16_sc0(const void* p){
    i4 r;
    asm volatile("global_load_dwordx4 %0, %1, off sc0" : "=v"(r) : "v"(p) : "memory");
    return r;
}
__device__ __forceinline__ void store2_sc0(void* p, unsigned v){
    asm volatile("global_store_short %0, %1, off sc0" : : "v"(p), "v"(v) : "memory");
}
__device__ __forceinline__ void store1_sc0(void* p, unsigned v){
    asm volatile("global_store_byte %0, %1, off sc0" : : "v"(p), "v"(v) : "memory");
}
__device__ __forceinline__ unsigned load1_sc0_wait(const void* p){
    unsigned r;
    asm volatile("global_load_ubyte %0, %1, off sc0\n\ts_waitcnt vmcnt(0)"
                 : "=v"(r) : "v"(p) : "memory");
    return r;
}
__device__ __forceinline__ void wait_vm0(){
    asm volatile("s_waitcnt vmcnt(0)" ::: "memory");
}

// ---------------------------------------------------------------- init
__global__ void init_kernel(const float* __restrict__ projW,
                            float* __restrict__ out,
                            unsigned int* __restrict__ setup,   // [0]=winner, [1..8]=xcd tickets
                            unsigned char* __restrict__ flags,  // [T_][WFLAGS] bytes
                            unsigned short* __restrict__ h0,
                            unsigned short* __restrict__ Wt)
{
    const int i = blockIdx.x * 256 + threadIdx.x;   // grid covers 65536
    if (i < 1024) setup[i] = 0u;
    if (i < T_ * WFLAGS) flags[i] = 0;
    if (i == 0) out[0] = 0.f;
    if (i < B_ * H_) h0[i] = 0;                     // h_all step 0 = zeros
    if (i < 64 * H_){                               // Wt[c][k] = proj_W[k][c], bf16, pad c>=50 with 0
        const int c = i >> 9;
        const int k = i & 511;
        const float v = (c < L_) ? projW[k * L_ + c] : 0.f;
        Wt[i] = f2bf(v);
    }
}

// ---------------------------------------------------------------- LSTM recurrence (cooperative, single-XCD)
// 256 blocks launched; XCD election via tickets (see round-0 comments). All
// h-exchange / flags use sc0-only ops through the winner XCD's shared L2.
//
// Restructure vs round 0 (latency chain, not protocol):
//  * x-row (word_embed gather) for t+1 prefetched at TOP of iteration t -> its
//    L3/HBM RT hides under poll + h-phase; tail is f2bf+MFMA only.
//  * all 16 h loads issued before a single vmcnt(0) (was 2 serialized groups).
//  * per-WAVE byte flags: notify right after own store-ack; no __syncthreads in
//    the loop. Consumer needs only the 64 producer waves with matching nt ->
//    one flag per lane. Byte flags keep ws layout identical to round 0.
//  * each lane stores its own 2 h values as 2B sc0 stores (no shuffle pack).
//  * activations via native v_exp/v_rcp; MFMA in 4 independent chains.
//  * poll guard 1<<18: worst-case livelock terminates (wrong answer + counters)
//    instead of a watchdog hang; never binding in normal operation.
__global__ void __launch_bounds__(256, 1) lstm_kernel(
    const int* __restrict__ q, const int* __restrict__ lengths,
    const float* __restrict__ we, const float* __restrict__ lstmW,
    const float* __restrict__ lstmB,
    unsigned short* __restrict__ h_all, unsigned char* __restrict__ flags,
    unsigned int* __restrict__ setup)
{
    const int tid  = threadIdx.x;

    __shared__ int s_role;
    if (tid == 0){
        int xcd;
        asm volatile("s_getreg_b32 %0, hwreg(HW_REG_XCC_ID)" : "=s"(xcd));
        xcd &= 7;
        unsigned tk = __hip_atomic_fetch_add(&setup[1 + xcd], 1u,
                                             __ATOMIC_RELAXED, __HIP_MEMORY_SCOPE_AGENT);
        int role = -1;
        if (tk < (unsigned)NBLK){
            if (tk == NBLK - 1){
                unsigned exp = 0u;
                __hip_atomic_compare_exchange_strong(&setup[0], &exp, (unsigned)(xcd + 1),
                    __ATOMIC_RELAXED, __ATOMIC_RELAXED, __HIP_MEMORY_SCOPE_AGENT);
            }
            unsigned w = 0u; int guard = 0;
            for (;;){
                w = __hip_atomic_load(&setup[0], __ATOMIC_RELAXED, __HIP_MEMORY_SCOPE_AGENT);
                if (w != 0u || ++guard > (1 << 24)) break;
                __builtin_amdgcn_s_sleep(2);
            }
            if (w == (unsigned)(xcd + 1)) role = (int)tk;
        }
        s_role = role;
    }
    __syncthreads();
    const int blk = s_role;          // worker slot 0..31, or -1
    if (blk < 0) return;

    const int wv   = tid >> 6;       // 0..3
    const int lane = tid & 63;
    const int nt = wv & 1, mpair = wv >> 1;   // n-half, m-tile pair
    const int l15 = lane & 15, quad = lane >> 4;

    // ---- A-operand mapping (lane&15 = m = z-col in tile; k = quad*8 + j)
    const int hcA0 = blk * 16 + (mpair * 2 + 0) * 4 + (l15 >> 2);
    const int hcA1 = blk * 16 + (mpair * 2 + 1) * 4 + (l15 >> 2);
    const int gA   = l15 & 3;
    const int colA0 = gA * H_ + hcA0;
    const int colA1 = gA * H_ + hcA1;

    short8 AW0[8], AW1[8], AH0[16], AH1[16];
#pragma unroll
    for (int kc = 0; kc < 8; ++kc){     // x-part rows 0..255
        short8 f0, f1;
#pragma unroll
        for (int j = 0; j < 8; ++j){
            const int r = kc * 32 + quad * 8 + j;
            f0[j] = (short)f2bf(lstmW[(size_t)r * 2048 + colA0]);
            f1[j] = (short)f2bf(lstmW[(size_t)r * 2048 + colA1]);
        }
        AW0[kc] = f0; AW1[kc] = f1;
    }
#pragma unroll
    for (int kc = 0; kc < 16; ++kc){    // h-part rows 256..767
        short8 f0, f1;
#pragma unroll
        for (int j = 0; j < 8; ++j){
            const int r = E_ + kc * 32 + quad * 8 + j;
            f0[j] = (short)f2bf(lstmW[(size_t)r * 2048 + colA0]);
            f1[j] = (short)f2bf(lstmW[(size_t)r * 2048 + colA1]);
        }
        AH0[kc] = f0; AH1[kc] = f1;
    }

    // ---- epilogue mapping (lane&15 = n = batch; D row quad*4+reg -> hc=quad, gate=reg)
    const int bE   = nt * 16 + l15;
    const int hcE0 = blk * 16 + mpair * 8 + quad;        // tile0
    const int hcE1 = blk * 16 + mpair * 8 + 4 + quad;    // tile1
    float bias0[4], bias1[4];
#pragma unroll
    for (int g = 0; g < 4; ++g){ bias0[g] = lstmB[g * H_ + hcE0]; bias1[g] = lstmB[g * H_ + hcE1]; }
    const int lenb = lengths[bE];

    float c0 = 0.f, c1 = 0.f, hp0 = 0.f, hp1 = 0.f;

    // pre-loop x-part for t=0 (cold path, plain loads)
    v4f accX0 = { bias0[0], bias0[1], bias0[2], bias0[3] };
    v4f accX1 = { bias1[0], bias1[1], bias1[2], bias1[3] };
    {
        const int qv = q[bE * T_];
        const v4f* wp = (const v4f*)(we + (size_t)qv * E_);
#pragma unroll
        for (int kc = 0; kc < 8; ++kc){
            const v4f e0 = wp[kc * 8 + quad * 2];
            const v4f e1 = wp[kc * 8 + quad * 2 + 1];
            short8 eb;
#pragma unroll
            for (int j = 0; j < 4; ++j){ eb[j] = (short)f2bf(e0[j]); eb[4 + j] = (short)f2bf(e1[j]); }
            accX0 = __builtin_amdgcn_mfma_f32_16x16x32_bf16(AW0[kc], eb, accX0, 0, 0, 0);
            accX1 = __builtin_amdgcn_mfma_f32_16x16x32_bf16(AW1[kc], eb, accX1, 0, 0, 0);
        }
    }

    int qnext = q[bE * T_ + 1];      // q for t+1 (prefetched one iter ahead)

    for (int t = 0; t < T_; ++t){
        // (A) issue x-row gather for t+1 NOW (plain cached loads; L3 RT hides
        // under poll + h-phase).
        i4 xf[16];
        {
            const v4f* wp = (const v4f*)(we + (size_t)qnext * E_);
#pragma unroll
            for (int kc = 0; kc < 8; ++kc){
                xf[2 * kc]     = *(const i4*)(wp + kc * 8 + quad * 2);
                xf[2 * kc + 1] = *(const i4*)(wp + kc * 8 + quad * 2 + 1);
            }
        }
        const int qnext2 = q[bE * T_ + ((t + 2 < T_) ? (t + 2) : (T_ - 1))];

        // (B) poll the 64 producer waves with matching nt: one flag per lane
        if (t > 0){
            const unsigned char* fl = flags + (unsigned)(t - 1) * WFLAGS + (lane * 2 + nt);
            int guard = 0;
            for (;;){
                const unsigned f = load1_sc0_wait(fl);
                if (__ballot(f != 0u) == 0xFFFFFFFFFFFFFFFFull) break;
                if (++guard > (1 << 18)) break;   // safety valve (never binding normally)
            }
        }

        // (C) all 16 h B-frag loads from L2 (sc0), ONE wait
        const unsigned short* hrow = h_all + (size_t)t * (B_ * H_) + (size_t)bE * H_;
        i4 hbuf[16];
#pragma unroll
        for (int kc = 0; kc < 16; ++kc)
            hbuf[kc] = load16_sc0(hrow + kc * 32 + quad * 8);
        wait_vm0();

        // (D) 32 MFMA in 4 independent chains (kc even/odd x 2 tiles)
        v4f a0e = accX0, a1e = accX1;
        v4f a0o = { 0.f, 0.f, 0.f, 0.f }, a1o = { 0.f, 0.f, 0.f, 0.f };
#pragma unroll
        for (int kc = 0; kc < 16; kc += 2){
            union { i4 i; short8 s; } cv0, cv1; cv0.i = hbuf[kc]; cv1.i = hbuf[kc + 1];
            a0e = __builtin_amdgcn_mfma_f32_16x16x32_bf16(AH0[kc],     cv0.s, a0e, 0, 0, 0);
            a1e = __builtin_amdgcn_mfma_f32_16x16x32_bf16(AH1[kc],     cv0.s, a1e, 0, 0, 0);
            a0o = __builtin_amdgcn_mfma_f32_16x16x32_bf16(AH0[kc + 1], cv1.s, a0o, 0, 0, 0);
            a1o = __builtin_amdgcn_mfma_f32_16x16x32_bf16(AH1[kc + 1], cv1.s, a1o, 0, 0, 0);
        }
        const v4f acc0 = a0e + a0o;
        const v4f acc1 = a1e + a1o;

        // (E) gates per tile: i,j,f,o = acc[0..3]; native exp/rcp
        const bool msk = (t < lenb);
        const float cn0 = c0 * fastsig(acc0[2] + 1.0f) + fastsig(acc0[0]) * fasttanh(acc0[1]);
        const float hn0 = fasttanh(cn0) * fastsig(acc0[3]);
        c0 = msk ? cn0 : c0;
        const float h20 = msk ? hn0 : hp0; hp0 = h20;
        const float cn1 = c1 * fastsig(acc1[2] + 1.0f) + fastsig(acc1[0]) * fasttanh(acc1[1]);
        const float hn1 = fasttanh(cn1) * fastsig(acc1[3]);
        c1 = msk ? cn1 : c1;
        const float h21 = msk ? hn1 : hp1; hp1 = h21;

        // (F) direct 2B sc0 stores: each lane owns (bE, hcE0) and (bE, hcE1)
        unsigned short* hdst = h_all + (size_t)(t + 1) * (B_ * H_) + (size_t)bE * H_;
        store2_sc0(hdst + hcE0, (unsigned)f2bf(h20));
        store2_sc0(hdst + hcE1, (unsigned)f2bf(h21));
        wait_vm0();                      // h stores committed in L2
        if (lane == 0)
            store1_sc0(&flags[(unsigned)t * WFLAGS + (unsigned)(blk * 4 + wv)], 1u);

        // (G) tail (in notify slack): convert prefetched x-row, accX for t+1
        if (t + 1 < T_){
            accX0 = (v4f){ bias0[0], bias0[1], bias0[2], bias0[3] };
            accX1 = (v4f){ bias1[0], bias1[1], bias1[2], bias1[3] };
#pragma unroll
            for (int kc = 0; kc < 8; ++kc){
                union { i4 i; v4f f; } u0, u1; u0.i = xf[2 * kc]; u1.i = xf[2 * kc + 1];
                short8 eb;
#pragma unroll
                for (int j = 0; j < 4; ++j){ eb[j] = (short)f2bf(u0.f[j]); eb[4 + j] = (short)f2bf(u1.f[j]); }
                accX0 = __builtin_amdgcn_mfma_f32_16x16x32_bf16(AW0[kc], eb, accX0, 0, 0, 0);
                accX1 = __builtin_amdgcn_mfma_f32_16x16x32_bf16(AW1[kc], eb, accX1, 0, 0, 0);
            }
        }
        qnext = qnext2;
    }
}

// ---------------------------------------------------------------- projection + relu + log-softmax + xent
__global__ void __launch_bounds__(256) loss_kernel(
    const int* __restrict__ a, const int* __restrict__ lengths,
    const float* __restrict__ projB,
    const unsigned short* __restrict__ h_all,
    const unsigned short* __restrict__ Wt,
    float* __restrict__ out)
{
    const int tid = threadIdx.x;
    const int wv = tid >> 6, lane = tid & 63;
    const int l15 = lane & 15, quad = lane >> 4;
    const int wgid = blockIdx.x * 4 + wv;            // 0..1023
    const int row0 = wgid * 16;

    const int rowA = row0 + l15;
    const int bA = rowA >> 9, tA = rowA & 511;
    const unsigned short* hrow = h_all + ((size_t)(tA + 1) * B_ + bA) * H_;

    v4f acc[4] = { {0,0,0,0}, {0,0,0,0}, {0,0,0,0}, {0,0,0,0} };
#pragma unroll
    for (int kc = 0; kc < 16; ++kc){
        const short8 af = *(const short8*)(hrow + kc * 32 + quad * 8);
#pragma unroll
        for (int ntl = 0; ntl < 4; ++ntl){
            const short8 bf = *(const short8*)(Wt + (size_t)(ntl * 16 + l15) * H_ + kc * 32 + quad * 8);
            acc[ntl] = __builtin_amdgcn_mfma_f32_16x16x32_bf16(af, bf, acc[ntl], 0, 0, 0);
        }
    }

    float pb[4]; bool cv[4];
#pragma unroll
    for (int ntl = 0; ntl < 4; ++ntl){
        const int c = ntl * 16 + l15;
        cv[ntl] = (c < L_);
        pb[ntl] = cv[ntl] ? projB[c] : 0.f;
    }

#pragma unroll
    for (int r = 0; r < 4; ++r){
        const int row = row0 + quad * 4 + r;
        const int b = row >> 9, t = row & 511;
        const int len = lengths[b];
        const bool valid = (t < len);

        float lv[4];
#pragma unroll
        for (int ntl = 0; ntl < 4; ++ntl)
            lv[ntl] = fmaxf(acc[ntl][r] + pb[ntl], 0.f);   // relu(logits)

        float mx = -1e30f;
#pragma unroll
        for (int ntl = 0; ntl < 4; ++ntl) if (cv[ntl]) mx = fmaxf(mx, lv[ntl]);
        mx = qredmax(mx);
        float se = 0.f;
#pragma unroll
        for (int ntl = 0; ntl < 4; ++ntl) if (cv[ntl]) se += expf(lv[ntl] - mx);
        se = qredsum(se);
        const int lbl = a[row];
        float cand = 0.f;
#pragma unroll
        for (int ntl = 0; ntl < 4; ++ntl) if (ntl * 16 + l15 == lbl) cand = lv[ntl];
        const float llbl = qredsum(cand);

        if (valid && l15 == 0){
            const float xent = logf(se) + mx - llbl;      // -log_softmax[label]
            atomicAdd(out, xent / ((float)len * 32.0f));
        }
    }
}

// ---------------------------------------------------------------- launch
extern "C" void kernel_launch(void* const* d_in, const int* in_sizes, int n_in,
                              void* d_out, int out_size, void* d_ws, size_t ws_size,
                              hipStream_t stream)
{
    const int*   q   = (const int*)d_in[0];
    const int*   a   = (const int*)d_in[1];
    const int*   len = (const int*)d_in[2];
    const float* we  = (const float*)d_in[3];
    const float* lW  = (const float*)d_in[4];
    const float* lB  = (const float*)d_in[5];
    const float* pW  = (const float*)d_in[6];
    const float* pB  = (const float*)d_in[7];
    float* out = (float*)d_out;

    unsigned char* ws = (unsigned char*)d_ws;
    unsigned int*   setup = (unsigned int*)ws;                       // 4 KiB
    unsigned char*  flags = (unsigned char*)(ws + 4096);             // 512*128 = 64 KiB
    unsigned short* h_all = (unsigned short*)(ws + 4096 + 65536);    // 513*32*512*2 B
    unsigned short* Wt    = (unsigned short*)(ws + 4096 + 65536 + (size_t)(T_ + 1) * B_ * H_ * 2);

    init_kernel<<<dim3(256), dim3(256), 0, stream>>>(pW, out, setup, flags, h_all, Wt);

    {
        const int* q_ = q; const int* len_ = len; const float* we_ = we;
        const float* lW_ = lW; const float* lB_ = lB;
        unsigned short* h_ = h_all; unsigned char* f_ = flags; unsigned int* s_ = setup;
        void* args[] = { (void*)&q_, (void*)&len_, (void*)&we_, (void*)&lW_,
                         (void*)&lB_, (void*)&h_, (void*)&f_, (void*)&s_ };
        hipLaunchCooperativeKernel((void*)lstm_kernel, dim3(NGRID), dim3(256),
                                   args, 0, stream);
    }

    loss_kernel<<<dim3(256), dim3(256), 0, stream>>>(a, len, pB, h_all, Wt, out);
}

// Round 3
// 2807.197 us; speedup vs baseline: 2283.0055x; 2283.0055x over previous
//
#include <hip/hip_runtime.h>
#include <hip/hip_bf16.h>

#define B_ 32
#define T_ 512
#define E_ 256
#define H_ 512
#define L_ 50
#define NBLK 32          // worker blocks (all on ONE XCD)
#define NGRID 256        // launched blocks; non-winners exit

typedef __attribute__((ext_vector_type(8))) short short8;
typedef __attribute__((ext_vector_type(4))) float v4f;
typedef __attribute__((ext_vector_type(4))) int i4;
typedef unsigned long long u64;

__device__ __forceinline__ unsigned short f2bf(float f){
    union { float f; unsigned u; } v; v.f = f;
    unsigned u = v.u;
    u += 0x7fffu + ((u >> 16) & 1u);   // RNE
    return (unsigned short)(u >> 16);
}
// native-transcendental activations: v_exp_f32 + v_rcp_f32 (~1e-6 rel err, far
// below the bf16 rounding already in the h pipeline; validated absmax=0 in r2)
__device__ __forceinline__ float fastsig(float x){
    return __builtin_amdgcn_rcpf(1.0f + __expf(-x));
}
__device__ __forceinline__ float fasttanh(float x){
    return 1.0f - 2.0f * __builtin_amdgcn_rcpf(__expf(2.0f * x) + 1.0f);
}

__device__ __forceinline__ float qredmax(float v){
    v = fmaxf(v, __shfl_xor(v, 1, 64));
    v = fmaxf(v, __shfl_xor(v, 2, 64));
    v = fmaxf(v, __shfl_xor(v, 4, 64));
    v = fmaxf(v, __shfl_xor(v, 8, 64));
    return v;
}
__device__ __forceinline__ float qredsum(float v){
    v += __shfl_xor(v, 1, 64);
    v += __shfl_xor(v, 2, 64);
    v += __shfl_xor(v, 4, 64);
    v += __shfl_xor(v, 8, 64);
    return v;
}

// sc0-only memory ops: bypass L1, hit the XCD-shared L2 (intra-XCD coherent).
__device__ __forceinline__ i4 load16_sc0(const void* p){
    i4 r;
    asm volatile("global_load_dwordx4 %0, %1, off sc0" : "=v"(r) : "v"(p) : "memory");
    return r;
}
__device__ __forceinline__ void store8_sc0(void* p, u64 v){
    asm volatile("global_store_dwordx2 %0, %1, off sc0" : : "v"(p), "v"(v) : "memory");
}
__device__ __forceinline__ void store4_sc0(void* p, unsigned v){
    asm volatile("global_store_dword %0, %1, off sc0" : : "v"(p), "v"(v) : "memory");
}
__device__ __forceinline__ unsigned load4_sc0_wait(const void* p){
    unsigned r;
    asm volatile("global_load_dword %0, %1, off sc0\n\ts_waitcnt vmcnt(0)"
                 : "=v"(r) : "v"(p) : "memory");
    return r;
}
__device__ __forceinline__ void wait_vm0(){
    asm volatile("s_waitcnt vmcnt(0)" ::: "memory");
}

// ---------------------------------------------------------------- init
__global__ void init_kernel(const float* __restrict__ projW,
                            float* __restrict__ out,
                            unsigned int* __restrict__ setup,   // [0]=winner, [1..8]=xcd tickets
                            unsigned int* __restrict__ flags,   // [T_][NBLK]
                            unsigned short* __restrict__ h0,
                            unsigned short* __restrict__ Wt)
{
    const int i = blockIdx.x * 256 + threadIdx.x;   // grid covers 32768
    if (i < 1024) setup[i] = 0u;
    if (i < T_ * NBLK) flags[i] = 0u;
    if (i == 0) out[0] = 0.f;
    if (i < B_ * H_) h0[i] = 0;                     // h_all step 0 = zeros
    if (i < 64 * H_){                               // Wt[c][k] = proj_W[k][c], bf16, pad c>=50 with 0
        const int c = i >> 9;
        const int k = i & 511;
        const float v = (c < L_) ? projW[k * L_ + c] : 0.f;
        Wt[i] = f2bf(v);
    }
}

// ---------------------------------------------------------------- LSTM recurrence (cooperative, single-XCD)
// Protocol is byte-identical to the proven round-0 version: dword block flags,
// lane<32 sleep-poll, u64 shuffle-packed h stores, __syncthreads + single flag
// store per block. (Rounds 1-2 post-mortem: per-wave BYTE flags + sleepless
// 64-lane poll starved the flag store's L2 line access -> guard expiry every
// step -> 1800x slowdown with correct results.)
//
// Kept intra-wave improvements (protocol-neutral):
//  * x-row (word_embed gather) for t+1 prefetched at TOP of iteration t -> its
//    L3/HBM RT hides under poll + h-phase; tail is f2bf+MFMA only.
//  * all 16 h loads issued before a single vmcnt(0) (was 2 serialized groups).
//  * activations via native v_exp/v_rcp (validated absmax=0 in round 2).
//  * MFMA in 4 independent chains (kc even/odd x 2 tiles).
__global__ void __launch_bounds__(256, 1) lstm_kernel(
    const int* __restrict__ q, const int* __restrict__ lengths,
    const float* __restrict__ we, const float* __restrict__ lstmW,
    const float* __restrict__ lstmB,
    unsigned short* __restrict__ h_all, unsigned int* __restrict__ flags,
    unsigned int* __restrict__ setup)
{
    const int tid  = threadIdx.x;

    __shared__ int s_role;
    if (tid == 0){
        int xcd;
        asm volatile("s_getreg_b32 %0, hwreg(HW_REG_XCC_ID)" : "=s"(xcd));
        xcd &= 7;
        unsigned tk = __hip_atomic_fetch_add(&setup[1 + xcd], 1u,
                                             __ATOMIC_RELAXED, __HIP_MEMORY_SCOPE_AGENT);
        int role = -1;
        if (tk < (unsigned)NBLK){
            if (tk == NBLK - 1){
                unsigned exp = 0u;
                __hip_atomic_compare_exchange_strong(&setup[0], &exp, (unsigned)(xcd + 1),
                    __ATOMIC_RELAXED, __ATOMIC_RELAXED, __HIP_MEMORY_SCOPE_AGENT);
            }
            unsigned w = 0u; int guard = 0;
            for (;;){
                w = __hip_atomic_load(&setup[0], __ATOMIC_RELAXED, __HIP_MEMORY_SCOPE_AGENT);
                if (w != 0u || ++guard > (1 << 24)) break;
                __builtin_amdgcn_s_sleep(2);
            }
            if (w == (unsigned)(xcd + 1)) role = (int)tk;
        }
        s_role = role;
    }
    __syncthreads();
    const int blk = s_role;          // worker slot 0..31, or -1
    if (blk < 0) return;

    const int wv   = tid >> 6;       // 0..3
    const int lane = tid & 63;
    const int nt = wv & 1, mpair = wv >> 1;   // n-half, m-tile pair
    const int l15 = lane & 15, quad = lane >> 4;

    // ---- A-operand mapping (lane&15 = m = z-col in tile; k = quad*8 + j)
    const int hcA0 = blk * 16 + (mpair * 2 + 0) * 4 + (l15 >> 2);
    const int hcA1 = blk * 16 + (mpair * 2 + 1) * 4 + (l15 >> 2);
    const int gA   = l15 & 3;
    const int colA0 = gA * H_ + hcA0;
    const int colA1 = gA * H_ + hcA1;

    short8 AW0[8], AW1[8], AH0[16], AH1[16];
#pragma unroll
    for (int kc = 0; kc < 8; ++kc){     // x-part rows 0..255
        short8 f0, f1;
#pragma unroll
        for (int j = 0; j < 8; ++j){
            const int r = kc * 32 + quad * 8 + j;
            f0[j] = (short)f2bf(lstmW[(size_t)r * 2048 + colA0]);
            f1[j] = (short)f2bf(lstmW[(size_t)r * 2048 + colA1]);
        }
        AW0[kc] = f0; AW1[kc] = f1;
    }
#pragma unroll
    for (int kc = 0; kc < 16; ++kc){    // h-part rows 256..767
        short8 f0, f1;
#pragma unroll
        for (int j = 0; j < 8; ++j){
            const int r = E_ + kc * 32 + quad * 8 + j;
            f0[j] = (short)f2bf(lstmW[(size_t)r * 2048 + colA0]);
            f1[j] = (short)f2bf(lstmW[(size_t)r * 2048 + colA1]);
        }
        AH0[kc] = f0; AH1[kc] = f1;
    }

    // ---- epilogue mapping (lane&15 = n = batch; D row quad*4+reg -> hc=quad, gate=reg)
    const int bE   = nt * 16 + l15;
    const int hcE0 = blk * 16 + (mpair * 2 + 0) * 4 + quad;
    const int hcE1 = blk * 16 + (mpair * 2 + 1) * 4 + quad;
    float bias0[4], bias1[4];
#pragma unroll
    for (int g = 0; g < 4; ++g){ bias0[g] = lstmB[g * H_ + hcE0]; bias1[g] = lstmB[g * H_ + hcE1]; }
    const int lenb = lengths[bE];

    float c0 = 0.f, c1 = 0.f, hp0 = 0.f, hp1 = 0.f;

    // pre-loop x-part for t=0 (cold path, plain loads)
    v4f accX0 = { bias0[0], bias0[1], bias0[2], bias0[3] };
    v4f accX1 = { bias1[0], bias1[1], bias1[2], bias1[3] };
    {
        const int qv = q[bE * T_];
        const v4f* wp = (const v4f*)(we + (size_t)qv * E_);
#pragma unroll
        for (int kc = 0; kc < 8; ++kc){
            const v4f e0 = wp[kc * 8 + quad * 2];
            const v4f e1 = wp[kc * 8 + quad * 2 + 1];
            short8 eb;
#pragma unroll
            for (int j = 0; j < 4; ++j){ eb[j] = (short)f2bf(e0[j]); eb[4 + j] = (short)f2bf(e1[j]); }
            accX0 = __builtin_amdgcn_mfma_f32_16x16x32_bf16(AW0[kc], eb, accX0, 0, 0, 0);
            accX1 = __builtin_amdgcn_mfma_f32_16x16x32_bf16(AW1[kc], eb, accX1, 0, 0, 0);
        }
    }

    int qnext = q[bE * T_ + 1];      // q for t+1 (prefetched one iter ahead)

    for (int t = 0; t < T_; ++t){
        // (A) issue x-row gather for t+1 NOW (plain cached loads; L3/HBM RT
        // hides under poll + h-phase; consumed only in the tail).
        i4 xf[16];
        {
            const v4f* wp = (const v4f*)(we + (size_t)qnext * E_);
#pragma unroll
            for (int kc = 0; kc < 8; ++kc){
                xf[2 * kc]     = *(const i4*)(wp + kc * 8 + quad * 2);
                xf[2 * kc + 1] = *(const i4*)(wp + kc * 8 + quad * 2 + 1);
            }
        }
        const int qnext2 = q[bE * T_ + ((t + 2 < T_) ? (t + 2) : (T_ - 1))];

        // (B) poll 32 producer flags from XCD-local L2 (lanes 0..31) — round-0 form
        if (t > 0){
            const unsigned int* fl = flags + (unsigned)(t - 1) * NBLK;
            int guard = 0;
            for (;;){
                unsigned f = 1u;
                if (lane < NBLK) f = load4_sc0_wait(fl + lane);
                if (__ballot(f != 0u) == 0xFFFFFFFFFFFFFFFFull) break;
                __builtin_amdgcn_s_sleep(1);
                if (++guard > (1 << 17)) break;   // safety valve (never binding normally)
            }
        }

        // (C) all 16 h B-frag loads from L2 (sc0), ONE wait
        const unsigned short* hrow = h_all + (size_t)t * (B_ * H_) + (size_t)bE * H_;
        i4 hbuf[16];
#pragma unroll
        for (int kc = 0; kc < 16; ++kc)
            hbuf[kc] = load16_sc0(hrow + kc * 32 + quad * 8);
        wait_vm0();

        // (D) 32 MFMA in 4 independent chains (kc even/odd x 2 tiles)
        v4f a0e = accX0, a1e = accX1;
        v4f a0o = { 0.f, 0.f, 0.f, 0.f }, a1o = { 0.f, 0.f, 0.f, 0.f };
#pragma unroll
        for (int kc = 0; kc < 16; kc += 2){
            union { i4 i; short8 s; } cv0, cv1; cv0.i = hbuf[kc]; cv1.i = hbuf[kc + 1];
            a0e = __builtin_amdgcn_mfma_f32_16x16x32_bf16(AH0[kc],     cv0.s, a0e, 0, 0, 0);
            a1e = __builtin_amdgcn_mfma_f32_16x16x32_bf16(AH1[kc],     cv0.s, a1e, 0, 0, 0);
            a0o = __builtin_amdgcn_mfma_f32_16x16x32_bf16(AH0[kc + 1], cv1.s, a0o, 0, 0, 0);
            a1o = __builtin_amdgcn_mfma_f32_16x16x32_bf16(AH1[kc + 1], cv1.s, a1o, 0, 0, 0);
        }
        const v4f acc0 = a0e + a0o;
        const v4f acc1 = a1e + a1o;

        // (E) gates per tile: i,j,f,o = acc[0..3]; native exp/rcp
        const bool msk = (t < lenb);
        const float cn0 = c0 * fastsig(acc0[2] + 1.0f) + fastsig(acc0[0]) * fasttanh(acc0[1]);
        const float hn0 = fasttanh(cn0) * fastsig(acc0[3]);
        c0 = msk ? cn0 : c0;
        const float h20 = msk ? hn0 : hp0; hp0 = h20;
        const float cn1 = c1 * fastsig(acc1[2] + 1.0f) + fastsig(acc1[0]) * fasttanh(acc1[1]);
        const float hn1 = fasttanh(cn1) * fastsig(acc1[3]);
        c1 = msk ? cn1 : c1;
        const float h21 = msk ? hn1 : hp1; hp1 = h21;

        // (F) pack 4 hc per tile into u64; quad0 stores tile0, quad1 stores tile1
        const unsigned hv0 = f2bf(h20), hv1 = f2bf(h21);
        const int a0 = __shfl((int)hv0, l15, 64),      a1 = __shfl((int)hv0, l15 + 16, 64);
        const int a2 = __shfl((int)hv0, l15 + 32, 64), a3 = __shfl((int)hv0, l15 + 48, 64);
        const int b0 = __shfl((int)hv1, l15, 64),      b1 = __shfl((int)hv1, l15 + 16, 64);
        const int b2 = __shfl((int)hv1, l15 + 32, 64), b3 = __shfl((int)hv1, l15 + 48, 64);
        unsigned short* dstBase = h_all + (size_t)(t + 1) * (B_ * H_) + (size_t)bE * H_
                                + blk * 16 + mpair * 8;
        if (quad == 0){
            const u64 pk = (u64)(unsigned short)a0 | ((u64)(unsigned short)a1 << 16)
                         | ((u64)(unsigned short)a2 << 32) | ((u64)(unsigned short)a3 << 48);
            store8_sc0(dstBase, pk);
        } else if (quad == 1){
            const u64 pk = (u64)(unsigned short)b0 | ((u64)(unsigned short)b1 << 16)
                         | ((u64)(unsigned short)b2 << 32) | ((u64)(unsigned short)b3 << 48);
            store8_sc0(dstBase + 4, pk);
        }
        wait_vm0();                      // h stores committed in L2
        __syncthreads();                 // all waves of block done
        if (tid == 0)
            store4_sc0(&flags[(unsigned)t * NBLK + blk], 1u);

        // (G) tail (in notify slack): convert prefetched x-row, accX for t+1
        if (t + 1 < T_){
            accX0 = (v4f){ bias0[0], bias0[1], bias0[2], bias0[3] };
            accX1 = (v4f){ bias1[0], bias1[1], bias1[2], bias1[3] };
#pragma unroll
            for (int kc = 0; kc < 8; ++kc){
                union { i4 i; v4f f; } u0, u1; u0.i = xf[2 * kc]; u1.i = xf[2 * kc + 1];
                short8 eb;
#pragma unroll
                for (int j = 0; j < 4; ++j){ eb[j] = (short)f2bf(u0.f[j]); eb[4 + j] = (short)f2bf(u1.f[j]); }
                accX0 = __builtin_amdgcn_mfma_f32_16x16x32_bf16(AW0[kc], eb, accX0, 0, 0, 0);
                accX1 = __builtin_amdgcn_mfma_f32_16x16x32_bf16(AW1[kc], eb, accX1, 0, 0, 0);
            }
        }
        qnext = qnext2;
    }
}

// ---------------------------------------------------------------- projection + relu + log-softmax + xent
__global__ void __launch_bounds__(256) loss_kernel(
    const int* __restrict__ a, const int* __restrict__ lengths,
    const float* __restrict__ projB,
    const unsigned short* __restrict__ h_all,
    const unsigned short* __restrict__ Wt,
    float* __restrict__ out)
{
    const int tid = threadIdx.x;
    const int wv = tid >> 6, lane = tid & 63;
    const int l15 = lane & 15, quad = lane >> 4;
    const int wgid = blockIdx.x * 4 + wv;            // 0..1023
    const int row0 = wgid * 16;

    const int rowA = row0 + l15;
    const int bA = rowA >> 9, tA = rowA & 511;
    const unsigned short* hrow = h_all + ((size_t)(tA + 1) * B_ + bA) * H_;

    v4f acc[4] = { {0,0,0,0}, {0,0,0,0}, {0,0,0,0}, {0,0,0,0} };
#pragma unroll
    for (int kc = 0; kc < 16; ++kc){
        const short8 af = *(const short8*)(hrow + kc * 32 + quad * 8);
#pragma unroll
        for (int ntl = 0; ntl < 4; ++ntl){
            const short8 bf = *(const short8*)(Wt + (size_t)(ntl * 16 + l15) * H_ + kc * 32 + quad * 8);
            acc[ntl] = __builtin_amdgcn_mfma_f32_16x16x32_bf16(af, bf, acc[ntl], 0, 0, 0);
        }
    }

    float pb[4]; bool cv[4];
#pragma unroll
    for (int ntl = 0; ntl < 4; ++ntl){
        const int c = ntl * 16 + l15;
        cv[ntl] = (c < L_);
        pb[ntl] = cv[ntl] ? projB[c] : 0.f;
    }

#pragma unroll
    for (int r = 0; r < 4; ++r){
        const int row = row0 + quad * 4 + r;
        const int b = row >> 9, t = row & 511;
        const int len = lengths[b];
        const bool valid = (t < len);

        float lv[4];
#pragma unroll
        for (int ntl = 0; ntl < 4; ++ntl)
            lv[ntl] = fmaxf(acc[ntl][r] + pb[ntl], 0.f);   // relu(logits)

        float mx = -1e30f;
#pragma unroll
        for (int ntl = 0; ntl < 4; ++ntl) if (cv[ntl]) mx = fmaxf(mx, lv[ntl]);
        mx = qredmax(mx);
        float se = 0.f;
#pragma unroll
        for (int ntl = 0; ntl < 4; ++ntl) if (cv[ntl]) se += expf(lv[ntl] - mx);
        se = qredsum(se);
        const int lbl = a[row];
        float cand = 0.f;
#pragma unroll
        for (int ntl = 0; ntl < 4; ++ntl) if (ntl * 16 + l15 == lbl) cand = lv[ntl];
        const float llbl = qredsum(cand);

        if (valid && l15 == 0){
            const float xent = logf(se) + mx - llbl;      // -log_softmax[label]
            atomicAdd(out, xent / ((float)len * 32.0f));
        }
    }
}

// ---------------------------------------------------------------- launch
extern "C" void kernel_launch(void* const* d_in, const int* in_sizes, int n_in,
                              void* d_out, int out_size, void* d_ws, size_t ws_size,
                              hipStream_t stream)
{
    const int*   q   = (const int*)d_in[0];
    const int*   a   = (const int*)d_in[1];
    const int*   len = (const int*)d_in[2];
    const float* we  = (const float*)d_in[3];
    const float* lW  = (const float*)d_in[4];
    const float* lB  = (const float*)d_in[5];
    const float* pW  = (const float*)d_in[6];
    const float* pB  = (const float*)d_in[7];
    float* out = (float*)d_out;

    unsigned char* ws = (unsigned char*)d_ws;
    unsigned int*   setup = (unsigned int*)ws;                       // 4 KiB
    unsigned int*   flags = (unsigned int*)(ws + 4096);              // 512*32*4 = 64 KiB
    unsigned short* h_all = (unsigned short*)(ws + 4096 + 65536);    // 513*32*512*2 B
    unsigned short* Wt    = (unsigned short*)(ws + 4096 + 65536 + (size_t)(T_ + 1) * B_ * H_ * 2);

    init_kernel<<<dim3(128), dim3(256), 0, stream>>>(pW, out, setup, flags, h_all, Wt);

    {
        const int* q_ = q; const int* len_ = len; const float* we_ = we;
        const float* lW_ = lW; const float* lB_ = lB;
        unsigned short* h_ = h_all; unsigned int* f_ = flags; unsigned int* s_ = setup;
        void* args[] = { (void*)&q_, (void*)&len_, (void*)&we_, (void*)&lW_,
                         (void*)&lB_, (void*)&h_, (void*)&f_, (void*)&s_ };
        hipLaunchCooperativeKernel((void*)lstm_kernel, dim3(NGRID), dim3(256),
                                   args, 0, stream);
    }

    loss_kernel<<<dim3(256), dim3(256), 0, stream>>>(a, len, pB, h_all, Wt, out);
}

// Round 4
// 2170.009 us; speedup vs baseline: 2953.3723x; 1.2936x over previous
//
#include <hip/hip_runtime.h>
#include <hip/hip_bf16.h>

#define B_ 32
#define T_ 512
#define E_ 256
#define H_ 512
#define L_ 50
#define V_ 50000
#define NBLK 32          // worker blocks (all on ONE XCD)
#define NGRID 256        // launched blocks; non-winners exit

typedef __attribute__((ext_vector_type(8))) short short8;
typedef __attribute__((ext_vector_type(4))) float v4f;
typedef __attribute__((ext_vector_type(4))) int i4;
typedef unsigned long long u64;

__device__ __forceinline__ unsigned short f2bf(float f){
    union { float f; unsigned u; } v; v.f = f;
    unsigned u = v.u;
    u += 0x7fffu + ((u >> 16) & 1u);   // RNE
    return (unsigned short)(u >> 16);
}
// native-transcendental activations: v_exp_f32 + v_rcp_f32 (~1e-6 rel err, far
// below the bf16 rounding already in the h pipeline; validated absmax=0 r2/r3)
__device__ __forceinline__ float fastsig(float x){
    return __builtin_amdgcn_rcpf(1.0f + __expf(-x));
}
__device__ __forceinline__ float fasttanh(float x){
    return 1.0f - 2.0f * __builtin_amdgcn_rcpf(__expf(2.0f * x) + 1.0f);
}

__device__ __forceinline__ float qredmax(float v){
    v = fmaxf(v, __shfl_xor(v, 1, 64));
    v = fmaxf(v, __shfl_xor(v, 2, 64));
    v = fmaxf(v, __shfl_xor(v, 4, 64));
    v = fmaxf(v, __shfl_xor(v, 8, 64));
    return v;
}
__device__ __forceinline__ float qredsum(float v){
    v += __shfl_xor(v, 1, 64);
    v += __shfl_xor(v, 2, 64);
    v += __shfl_xor(v, 4, 64);
    v += __shfl_xor(v, 8, 64);
    return v;
}

// sc0-only memory ops: bypass L1, hit the XCD-shared L2 (intra-XCD coherent).
__device__ __forceinline__ i4 load16_sc0(const void* p){
    i4 r;
    asm volatile("global_load_dwordx4 %0, %1, off sc0" : "=v"(r) : "v"(p) : "memory");
    return r;
}
__device__ __forceinline__ void store8_sc0(void* p, u64 v){
    asm volatile("global_store_dwordx2 %0, %1, off sc0" : : "v"(p), "v"(v) : "memory");
}
__device__ __forceinline__ void store4_sc0(void* p, unsigned v){
    asm volatile("global_store_dword %0, %1, off sc0" : : "v"(p), "v"(v) : "memory");
}
__device__ __forceinline__ unsigned load4_sc0_wait(const void* p){
    unsigned r;
    asm volatile("global_load_dword %0, %1, off sc0\n\ts_waitcnt vmcnt(0)"
                 : "=v"(r) : "v"(p) : "memory");
    return r;
}
__device__ __forceinline__ void wait_vm0(){
    asm volatile("s_waitcnt vmcnt(0)" ::: "memory");
}

// ---------------------------------------------------------------- init + we->bf16 convert
// grid 6400 x 256 = 1,638,400 threads; each converts 8 floats of word_embed.
__global__ void init_kernel(const float* __restrict__ projW,
                            const float* __restrict__ we,
                            float* __restrict__ out,
                            unsigned int* __restrict__ setup,   // [0]=winner, [1..8]=xcd tickets
                            unsigned int* __restrict__ flags,   // [NBLK] monotonic step tags
                            unsigned short* __restrict__ h0,
                            unsigned short* __restrict__ Wt,
                            unsigned short* __restrict__ we_bf)
{
    const int i = blockIdx.x * 256 + threadIdx.x;
    if (i < 1024) setup[i] = 0u;
    if (i < NBLK) flags[i] = 0u;
    if (i == 0) out[0] = 0.f;
    if (i < B_ * H_) h0[i] = 0;                     // h_all step 0 = zeros
    if (i < 64 * H_){                               // Wt[c][k] = proj_W[k][c], bf16, pad c>=50 with 0
        const int c = i >> 9;
        const int k = i & 511;
        const float v = (c < L_) ? projW[k * L_ + c] : 0.f;
        Wt[i] = f2bf(v);
    }
    if (i < (V_ * E_) / 8){                         // bf16 embedding table (same RNE as before)
        const v4f* src = (const v4f*)(we + (size_t)i * 8);
        const v4f a = src[0], b = src[1];
        short8 o;
#pragma unroll
        for (int j = 0; j < 4; ++j){ o[j] = (short)f2bf(a[j]); o[4 + j] = (short)f2bf(b[j]); }
        *(short8*)(we_bf + (size_t)i * 8) = o;
    }
}

// ---------------------------------------------------------------- LSTM recurrence (cooperative, single-XCD)
// Protocol shape identical to the proven round-0/3 version: dword block flags,
// lane<32 sleep-poll, u64 shuffle-packed h stores, __syncthreads + single flag
// store per block. Changes vs round 3 (both protocol-safe):
//  * MONOTONIC flags: flags[blk] holds t+1 after step t; consumer polls
//    f >= t. One 128B flag region stays L2-hot forever (round 3 polled a FRESH
//    cold line every step -> possible hidden L3/HBM RT inside the poll).
//    Ordering unchanged: h stores -> vmcnt0 -> syncthreads -> flag store.
//  * x-phase reads the precomputed bf16 embedding table: tail loses all 64
//    f2bf VALU ops (~384cy) and halves its load count. Bitwise-identical math.
__global__ void __launch_bounds__(256, 1) lstm_kernel(
    const int* __restrict__ q, const int* __restrict__ lengths,
    const unsigned short* __restrict__ we_bf, const float* __restrict__ lstmW,
    const float* __restrict__ lstmB,
    unsigned short* __restrict__ h_all, unsigned int* __restrict__ flags,
    unsigned int* __restrict__ setup)
{
    const int tid  = threadIdx.x;

    __shared__ int s_role;
    if (tid == 0){
        int xcd;
        asm volatile("s_getreg_b32 %0, hwreg(HW_REG_XCC_ID)" : "=s"(xcd));
        xcd &= 7;
        unsigned tk = __hip_atomic_fetch_add(&setup[1 + xcd], 1u,
                                             __ATOMIC_RELAXED, __HIP_MEMORY_SCOPE_AGENT);
        int role = -1;
        if (tk < (unsigned)NBLK){
            if (tk == NBLK - 1){
                unsigned exp = 0u;
                __hip_atomic_compare_exchange_strong(&setup[0], &exp, (unsigned)(xcd + 1),
                    __ATOMIC_RELAXED, __ATOMIC_RELAXED, __HIP_MEMORY_SCOPE_AGENT);
            }
            unsigned w = 0u; int guard = 0;
            for (;;){
                w = __hip_atomic_load(&setup[0], __ATOMIC_RELAXED, __HIP_MEMORY_SCOPE_AGENT);
                if (w != 0u || ++guard > (1 << 24)) break;
                __builtin_amdgcn_s_sleep(2);
            }
            if (w == (unsigned)(xcd + 1)) role = (int)tk;
        }
        s_role = role;
    }
    __syncthreads();
    const int blk = s_role;          // worker slot 0..31, or -1
    if (blk < 0) return;

    const int wv   = tid >> 6;       // 0..3
    const int lane = tid & 63;
    const int nt = wv & 1, mpair = wv >> 1;   // n-half, m-tile pair
    const int l15 = lane & 15, quad = lane >> 4;

    // ---- A-operand mapping (lane&15 = m = z-col in tile; k = quad*8 + j)
    const int hcA0 = blk * 16 + (mpair * 2 + 0) * 4 + (l15 >> 2);
    const int hcA1 = blk * 16 + (mpair * 2 + 1) * 4 + (l15 >> 2);
    const int gA   = l15 & 3;
    const int colA0 = gA * H_ + hcA0;
    const int colA1 = gA * H_ + hcA1;

    short8 AW0[8], AW1[8], AH0[16], AH1[16];
#pragma unroll
    for (int kc = 0; kc < 8; ++kc){     // x-part rows 0..255
        short8 f0, f1;
#pragma unroll
        for (int j = 0; j < 8; ++j){
            const int r = kc * 32 + quad * 8 + j;
            f0[j] = (short)f2bf(lstmW[(size_t)r * 2048 + colA0]);
            f1[j] = (short)f2bf(lstmW[(size_t)r * 2048 + colA1]);
        }
        AW0[kc] = f0; AW1[kc] = f1;
    }
#pragma unroll
    for (int kc = 0; kc < 16; ++kc){    // h-part rows 256..767
        short8 f0, f1;
#pragma unroll
        for (int j = 0; j < 8; ++j){
            const int r = E_ + kc * 32 + quad * 8 + j;
            f0[j] = (short)f2bf(lstmW[(size_t)r * 2048 + colA0]);
            f1[j] = (short)f2bf(lstmW[(size_t)r * 2048 + colA1]);
        }
        AH0[kc] = f0; AH1[kc] = f1;
    }

    // ---- epilogue mapping (lane&15 = n = batch; D row quad*4+reg -> hc=quad, gate=reg)
    const int bE   = nt * 16 + l15;
    const int hcE0 = blk * 16 + (mpair * 2 + 0) * 4 + quad;
    const int hcE1 = blk * 16 + (mpair * 2 + 1) * 4 + quad;
    float bias0[4], bias1[4];
#pragma unroll
    for (int g = 0; g < 4; ++g){ bias0[g] = lstmB[g * H_ + hcE0]; bias1[g] = lstmB[g * H_ + hcE1]; }
    const int lenb = lengths[bE];

    float c0 = 0.f, c1 = 0.f, hp0 = 0.f, hp1 = 0.f;

    // pre-loop x-part for t=0 (cold path)
    v4f accX0 = { bias0[0], bias0[1], bias0[2], bias0[3] };
    v4f accX1 = { bias1[0], bias1[1], bias1[2], bias1[3] };
    {
        const int qv = q[bE * T_];
        const short8* wp = (const short8*)(we_bf + (size_t)qv * E_);
#pragma unroll
        for (int kc = 0; kc < 8; ++kc){
            const short8 eb = wp[kc * 4 + quad];
            accX0 = __builtin_amdgcn_mfma_f32_16x16x32_bf16(AW0[kc], eb, accX0, 0, 0, 0);
            accX1 = __builtin_amdgcn_mfma_f32_16x16x32_bf16(AW1[kc], eb, accX1, 0, 0, 0);
        }
    }

    int qnext = q[bE * T_ + 1];      // q for t+1 (prefetched one iter ahead)

    for (int t = 0; t < T_; ++t){
        // (A) issue bf16 x-row loads for t+1 NOW (plain cached loads; RT hides
        // under poll + h-phase; consumed only in the tail).
        short8 xe[8];
        {
            const short8* wp = (const short8*)(we_bf + (size_t)qnext * E_);
#pragma unroll
            for (int kc = 0; kc < 8; ++kc) xe[kc] = wp[kc * 4 + quad];
        }
        const int qnext2 = q[bE * T_ + ((t + 2 < T_) ? (t + 2) : (T_ - 1))];

        // (B) poll 32 monotonic producer flags (lanes 0..31): f >= t means
        // h[t] is committed by that block. Flag region is 128B, stays L2-hot.
        if (t > 0){
            int guard = 0;
            for (;;){
                unsigned f = 0xFFFFFFFFu;
                if (lane < NBLK) f = load4_sc0_wait(flags + lane);
                if (__ballot(f >= (unsigned)t) == 0xFFFFFFFFFFFFFFFFull) break;
                __builtin_amdgcn_s_sleep(1);
                if (++guard > (1 << 17)) break;   // safety valve (never binding normally)
            }
        }

        // (C) all 16 h B-frag loads from L2 (sc0), ONE wait
        const unsigned short* hrow = h_all + (size_t)t * (B_ * H_) + (size_t)bE * H_;
        i4 hbuf[16];
#pragma unroll
        for (int kc = 0; kc < 16; ++kc)
            hbuf[kc] = load16_sc0(hrow + kc * 32 + quad * 8);
        wait_vm0();

        // (D) 32 MFMA in 4 independent chains (kc even/odd x 2 tiles)
        v4f a0e = accX0, a1e = accX1;
        v4f a0o = { 0.f, 0.f, 0.f, 0.f }, a1o = { 0.f, 0.f, 0.f, 0.f };
#pragma unroll
        for (int kc = 0; kc < 16; kc += 2){
            union { i4 i; short8 s; } cv0, cv1; cv0.i = hbuf[kc]; cv1.i = hbuf[kc + 1];
            a0e = __builtin_amdgcn_mfma_f32_16x16x32_bf16(AH0[kc],     cv0.s, a0e, 0, 0, 0);
            a1e = __builtin_amdgcn_mfma_f32_16x16x32_bf16(AH1[kc],     cv0.s, a1e, 0, 0, 0);
            a0o = __builtin_amdgcn_mfma_f32_16x16x32_bf16(AH0[kc + 1], cv1.s, a0o, 0, 0, 0);
            a1o = __builtin_amdgcn_mfma_f32_16x16x32_bf16(AH1[kc + 1], cv1.s, a1o, 0, 0, 0);
        }
        const v4f acc0 = a0e + a0o;
        const v4f acc1 = a1e + a1o;

        // (E) gates per tile: i,j,f,o = acc[0..3]; native exp/rcp
        const bool msk = (t < lenb);
        const float cn0 = c0 * fastsig(acc0[2] + 1.0f) + fastsig(acc0[0]) * fasttanh(acc0[1]);
        const float hn0 = fasttanh(cn0) * fastsig(acc0[3]);
        c0 = msk ? cn0 : c0;
        const float h20 = msk ? hn0 : hp0; hp0 = h20;
        const float cn1 = c1 * fastsig(acc1[2] + 1.0f) + fastsig(acc1[0]) * fasttanh(acc1[1]);
        const float hn1 = fasttanh(cn1) * fastsig(acc1[3]);
        c1 = msk ? cn1 : c1;
        const float h21 = msk ? hn1 : hp1; hp1 = h21;

        // (F) pack 4 hc per tile into u64; quad0 stores tile0, quad1 stores tile1
        const unsigned hv0 = f2bf(h20), hv1 = f2bf(h21);
        const int a0 = __shfl((int)hv0, l15, 64),      a1 = __shfl((int)hv0, l15 + 16, 64);
        const int a2 = __shfl((int)hv0, l15 + 32, 64), a3 = __shfl((int)hv0, l15 + 48, 64);
        const int b0 = __shfl((int)hv1, l15, 64),      b1 = __shfl((int)hv1, l15 + 16, 64);
        const int b2 = __shfl((int)hv1, l15 + 32, 64), b3 = __shfl((int)hv1, l15 + 48, 64);
        unsigned short* dstBase = h_all + (size_t)(t + 1) * (B_ * H_) + (size_t)bE * H_
                                + blk * 16 + mpair * 8;
        if (quad == 0){
            const u64 pk = (u64)(unsigned short)a0 | ((u64)(unsigned short)a1 << 16)
                         | ((u64)(unsigned short)a2 << 32) | ((u64)(unsigned short)a3 << 48);
            store8_sc0(dstBase, pk);
        } else if (quad == 1){
            const u64 pk = (u64)(unsigned short)b0 | ((u64)(unsigned short)b1 << 16)
                         | ((u64)(unsigned short)b2 << 32) | ((u64)(unsigned short)b3 << 48);
            store8_sc0(dstBase + 4, pk);
        }
        wait_vm0();                      // h stores committed in L2
        __syncthreads();                 // all waves of block done
        if (tid == 0)
            store4_sc0(&flags[blk], (unsigned)(t + 1));

        // (G) tail (in notify slack): 16 MFMA on prefetched bf16 x-row
        if (t + 1 < T_){
            accX0 = (v4f){ bias0[0], bias0[1], bias0[2], bias0[3] };
            accX1 = (v4f){ bias1[0], bias1[1], bias1[2], bias1[3] };
#pragma unroll
            for (int kc = 0; kc < 8; ++kc){
                accX0 = __builtin_amdgcn_mfma_f32_16x16x32_bf16(AW0[kc], xe[kc], accX0, 0, 0, 0);
                accX1 = __builtin_amdgcn_mfma_f32_16x16x32_bf16(AW1[kc], xe[kc], accX1, 0, 0, 0);
            }
        }
        qnext = qnext2;
    }
}

// ---------------------------------------------------------------- projection + relu + log-softmax + xent
__global__ void __launch_bounds__(256) loss_kernel(
    const int* __restrict__ a, const int* __restrict__ lengths,
    const float* __restrict__ projB,
    const unsigned short* __restrict__ h_all,
    const unsigned short* __restrict__ Wt,
    float* __restrict__ out)
{
    const int tid = threadIdx.x;
    const int wv = tid >> 6, lane = tid & 63;
    const int l15 = lane & 15, quad = lane >> 4;
    const int wgid = blockIdx.x * 4 + wv;            // 0..1023
    const int row0 = wgid * 16;

    const int rowA = row0 + l15;
    const int bA = rowA >> 9, tA = rowA & 511;
    const unsigned short* hrow = h_all + ((size_t)(tA + 1) * B_ + bA) * H_;

    v4f acc[4] = { {0,0,0,0}, {0,0,0,0}, {0,0,0,0}, {0,0,0,0} };
#pragma unroll
    for (int kc = 0; kc < 16; ++kc){
        const short8 af = *(const short8*)(hrow + kc * 32 + quad * 8);
#pragma unroll
        for (int ntl = 0; ntl < 4; ++ntl){
            const short8 bf = *(const short8*)(Wt + (size_t)(ntl * 16 + l15) * H_ + kc * 32 + quad * 8);
            acc[ntl] = __builtin_amdgcn_mfma_f32_16x16x32_bf16(af, bf, acc[ntl], 0, 0, 0);
        }
    }

    float pb[4]; bool cv[4];
#pragma unroll
    for (int ntl = 0; ntl < 4; ++ntl){
        const int c = ntl * 16 + l15;
        cv[ntl] = (c < L_);
        pb[ntl] = cv[ntl] ? projB[c] : 0.f;
    }

#pragma unroll
    for (int r = 0; r < 4; ++r){
        const int row = row0 + quad * 4 + r;
        const int b = row >> 9, t = row & 511;
        const int len = lengths[b];
        const bool valid = (t < len);

        float lv[4];
#pragma unroll
        for (int ntl = 0; ntl < 4; ++ntl)
            lv[ntl] = fmaxf(acc[ntl][r] + pb[ntl], 0.f);   // relu(logits)

        float mx = -1e30f;
#pragma unroll
        for (int ntl = 0; ntl < 4; ++ntl) if (cv[ntl]) mx = fmaxf(mx, lv[ntl]);
        mx = qredmax(mx);
        float se = 0.f;
#pragma unroll
        for (int ntl = 0; ntl < 4; ++ntl) if (cv[ntl]) se += expf(lv[ntl] - mx);
        se = qredsum(se);
        const int lbl = a[row];
        float cand = 0.f;
#pragma unroll
        for (int ntl = 0; ntl < 4; ++ntl) if (ntl * 16 + l15 == lbl) cand = lv[ntl];
        const float llbl = qredsum(cand);

        if (valid && l15 == 0){
            const float xent = logf(se) + mx - llbl;      // -log_softmax[label]
            atomicAdd(out, xent / ((float)len * 32.0f));
        }
    }
}

// ---------------------------------------------------------------- launch
extern "C" void kernel_launch(void* const* d_in, const int* in_sizes, int n_in,
                              void* d_out, int out_size, void* d_ws, size_t ws_size,
                              hipStream_t stream)
{
    const int*   q   = (const int*)d_in[0];
    const int*   a   = (const int*)d_in[1];
    const int*   len = (const int*)d_in[2];
    const float* we  = (const float*)d_in[3];
    const float* lW  = (const float*)d_in[4];
    const float* lB  = (const float*)d_in[5];
    const float* pW  = (const float*)d_in[6];
    const float* pB  = (const float*)d_in[7];
    float* out = (float*)d_out;

    unsigned char* ws = (unsigned char*)d_ws;
    unsigned int*   setup = (unsigned int*)ws;                       // 4 KiB
    unsigned int*   flags = (unsigned int*)(ws + 4096);              // 32 dwords (4 KiB reserved)
    unsigned short* h_all = (unsigned short*)(ws + 8192);            // 513*32*512*2 B = 16.84 MB
    unsigned short* Wt    = (unsigned short*)(ws + 8192 + (size_t)(T_ + 1) * B_ * H_ * 2);  // 64 KiB
    unsigned short* we_bf = (unsigned short*)(ws + 8192 + (size_t)(T_ + 1) * B_ * H_ * 2 + 65536); // 25.6 MB

    init_kernel<<<dim3(6400), dim3(256), 0, stream>>>(pW, we, out, setup, flags, h_all, Wt, we_bf);

    {
        const int* q_ = q; const int* len_ = len; const unsigned short* we_ = we_bf;
        const float* lW_ = lW; const float* lB_ = lB;
        unsigned short* h_ = h_all; unsigned int* f_ = flags; unsigned int* s_ = setup;
        void* args[] = { (void*)&q_, (void*)&len_, (void*)&we_, (void*)&lW_,
                         (void*)&lB_, (void*)&h_, (void*)&f_, (void*)&s_ };
        hipLaunchCooperativeKernel((void*)lstm_kernel, dim3(NGRID), dim3(256),
                                   args, 0, stream);
    }

    loss_kernel<<<dim3(256), dim3(256), 0, stream>>>(a, len, pB, h_all, Wt, out);
}